// Round 5
// baseline (241.625 us; speedup 1.0000x reference)
//
#include <hip/hip_runtime.h>
#include <math.h>

#define H      2880
#define H4     720
#define NTOK   16384
#define NEXP   128
#define NCHUNK 90

typedef __attribute__((ext_vector_type(8)))  short bf16x8;
typedef __attribute__((ext_vector_type(16))) float f32x16;

union FragU { unsigned int u[4]; bf16x8 v; };

// hi = top 16 bits of fp32 (bf16 truncation); lo = fl_bf16(x - hi).
// Dropped terms ~2^-17|x||w| -> logit err ~2e-5; exact ranking restored by fp64 fixup.
__device__ inline bf16x8 pack_hi2(float4 a, float4 b) {
    const float f[8] = {a.x,a.y,a.z,a.w,b.x,b.y,b.z,b.w};
    FragU r;
#pragma unroll
    for (int j = 0; j < 4; ++j) {
        unsigned u0 = __float_as_uint(f[2*j]);
        unsigned u1 = __float_as_uint(f[2*j+1]);
        r.u[j] = (u1 & 0xFFFF0000u) | (u0 >> 16);
    }
    return r.v;
}
__device__ inline bf16x8 pack_lo2(float4 a, float4 b) {
    const float f[8] = {a.x,a.y,a.z,a.w,b.x,b.y,b.z,b.w};
    FragU r;
#pragma unroll
    for (int j = 0; j < 4; ++j) {
        float x0 = f[2*j],   h0 = __uint_as_float(__float_as_uint(x0) & 0xFFFF0000u);
        float x1 = f[2*j+1], h1 = __uint_as_float(__float_as_uint(x1) & 0xFFFF0000u);
        unsigned l0 = __float_as_uint(x0 - h0);
        unsigned l1 = __float_as_uint(x1 - h1);
        r.u[j] = (l1 & 0xFFFF0000u) | (l0 >> 16);
    }
    return r.v;
}

// ---------------- Kernel 0: one-time w -> bf16 hi/lo planes ----------------
__global__ __launch_bounds__(256) void wconv(
    const float* __restrict__ w, short* __restrict__ whi, short* __restrict__ wlo)
{
    const int i = blockIdx.x * 256 + threadIdx.x;      // 46080 threads, 8 floats each
    const float4* wg = (const float4*)w;
    const float4 a = wg[2*i], b = wg[2*i+1];
    *(bf16x8*)(whi + (size_t)i*8) = pack_hi2(a, b);
    *(bf16x8*)(wlo + (size_t)i*8) = pack_lo2(a, b);
}

// ---------------- Kernel 1: barrier-free MFMA GEMM, split-K ----------------
// Each wave: 32 tokens x 64 experts (2 column tiles). No LDS, no __syncthreads.
__global__ __launch_bounds__(256) void router_gemm_mfma(
    const float* __restrict__ x,        // [NTOK][H] fp32
    const short* __restrict__ whi,      // [NEXP][H] bf16 hi
    const short* __restrict__ wlo,      // [NEXP][H] bf16 lo
    float* __restrict__ p0,
    float* __restrict__ pws)
{
    const int tid  = threadIdx.x;
    const int lane = tid & 63;
    const int wv   = tid >> 6;
    const int bm   = blockIdx.x;        // 0..255 (64-token tiles)
    const int z    = blockIdx.y;
    const int ks   = gridDim.y;

    const int t0 = bm * 64 + (wv >> 1) * 32;
    const int e0 = (wv & 1) * 64;

    const int base = NCHUNK / ks, rem = NCHUNK % ks;
    const int c0 = z * base + (z < rem ? z : rem);
    const int c1 = c0 + base + (z < rem ? 1 : 0);

    float* outp = (z == 0) ? p0 : (pws + (size_t)(z - 1) * NTOK * NEXP);

    const int row = lane & 31;          // token row / expert col within tile
    const int kh  = lane >> 5;          // k-half

    const float4* xg = (const float4*)x + (size_t)(t0 + row) * H4;
    const size_t wr0 = (size_t)(e0 + row)      * H;
    const size_t wr1 = (size_t)(e0 + 32 + row) * H;

    f32x16 acc0, acc1;
#pragma unroll
    for (int r = 0; r < 16; ++r) { acc0[r] = 0.0f; acc1[r] = 0.0f; }

    for (int c = c0; c < c1; ++c) {
        const int kb = c * 32 + kh * 8;

        // B frags (bf16, precomputed): 16B aligned contiguous loads
        const bf16x8 bh00 = *(const bf16x8*)(whi + wr0 + kb);
        const bf16x8 bh01 = *(const bf16x8*)(whi + wr0 + kb + 16);
        const bf16x8 bl00 = *(const bf16x8*)(wlo + wr0 + kb);
        const bf16x8 bl01 = *(const bf16x8*)(wlo + wr0 + kb + 16);
        const bf16x8 bh10 = *(const bf16x8*)(whi + wr1 + kb);
        const bf16x8 bh11 = *(const bf16x8*)(whi + wr1 + kb + 16);
        const bf16x8 bl10 = *(const bf16x8*)(wlo + wr1 + kb);
        const bf16x8 bl11 = *(const bf16x8*)(wlo + wr1 + kb + 16);

        // A: 32 fp32 of this chunk for my row, hi/lo packed in-reg (R4-proven layout)
        const float4* xp = xg + c * 8 + kh * 2;
        const float4 x0 = xp[0], x1 = xp[1];    // k-step 0
        const float4 x2 = xp[4], x3 = xp[5];    // k-step 1
        const bf16x8 ah0 = pack_hi2(x0, x1), al0 = pack_lo2(x0, x1);
        const bf16x8 ah1 = pack_hi2(x2, x3), al1 = pack_lo2(x2, x3);

        acc0 = __builtin_amdgcn_mfma_f32_32x32x16_bf16(ah0, bh00, acc0, 0, 0, 0);
        acc0 = __builtin_amdgcn_mfma_f32_32x32x16_bf16(al0, bh00, acc0, 0, 0, 0);
        acc0 = __builtin_amdgcn_mfma_f32_32x32x16_bf16(ah0, bl00, acc0, 0, 0, 0);
        acc0 = __builtin_amdgcn_mfma_f32_32x32x16_bf16(ah1, bh01, acc0, 0, 0, 0);
        acc0 = __builtin_amdgcn_mfma_f32_32x32x16_bf16(al1, bh01, acc0, 0, 0, 0);
        acc0 = __builtin_amdgcn_mfma_f32_32x32x16_bf16(ah1, bl01, acc0, 0, 0, 0);

        acc1 = __builtin_amdgcn_mfma_f32_32x32x16_bf16(ah0, bh10, acc1, 0, 0, 0);
        acc1 = __builtin_amdgcn_mfma_f32_32x32x16_bf16(al0, bh10, acc1, 0, 0, 0);
        acc1 = __builtin_amdgcn_mfma_f32_32x32x16_bf16(ah0, bl10, acc1, 0, 0, 0);
        acc1 = __builtin_amdgcn_mfma_f32_32x32x16_bf16(ah1, bh11, acc1, 0, 0, 0);
        acc1 = __builtin_amdgcn_mfma_f32_32x32x16_bf16(al1, bh11, acc1, 0, 0, 0);
        acc1 = __builtin_amdgcn_mfma_f32_32x32x16_bf16(ah1, bl11, acc1, 0, 0, 0);
    }

    // D layout (32x32): col = lane&31, row = (r&3) + 8*(r>>2) + 4*(lane>>5)  [R4-verified]
    const int ecol  = lane & 31;
    const int rbase = t0 + 4 * (lane >> 5);
#pragma unroll
    for (int r = 0; r < 16; ++r) {
        const int orow = rbase + (r & 3) + 8 * (r >> 2);
        outp[(size_t)orow * NEXP + e0 + ecol]      = acc0[r];
        outp[(size_t)orow * NEXP + e0 + 32 + ecol] = acc1[r];
    }
}

// ---------------- Kernel 2: reduce slices + bias -> logits; approx top-8 (wave-parallel) -----
__global__ __launch_bounds__(256) void reduce_cand(
    float* __restrict__ p0,             // partial 0 -> final logits in place
    const float* __restrict__ pws,
    const float* __restrict__ bias,
    int* __restrict__ cand,             // [NTOK][8]
    int ks)
{
    const int tid = threadIdx.x;
    const int tok = blockIdx.x * 8 + (tid >> 5);
    const int l   = tid & 31;           // lane within 32-lane token group

    float4* row = (float4*)p0 + (size_t)tok * 32 + l;
    float4 s = row[0];
    for (int zz = 1; zz < ks; ++zz) {
        const float4 pz = ((const float4*)(pws + (size_t)(zz - 1) * NTOK * NEXP))[(size_t)tok * 32 + l];
        s.x += pz.x; s.y += pz.y; s.z += pz.z; s.w += pz.w;
    }
    const float4 bb = ((const float4*)bias)[l];
    s.x += bb.x; s.y += bb.y; s.z += bb.z; s.w += bb.w;
    row[0] = s;                         // final (approx) logits

    float v[4] = {s.x, s.y, s.z, s.w};  // my 4 experts: 4l..4l+3
    int out[8];
#pragma unroll
    for (int r = 0; r < 8; ++r) {
        // local argmax (strict > keeps lowest j on ties)
        float lv = v[0]; int lj = 0;
#pragma unroll
        for (int j = 1; j < 4; ++j) if (v[j] > lv) { lv = v[j]; lj = j; }
        int le = l * 4 + lj;
        // 32-lane butterfly arg-max, tie -> lower expert index
#pragma unroll
        for (int m = 1; m < 32; m <<= 1) {
            const float ov = __shfl_xor(lv, m, 32);
            const int   oe = __shfl_xor(le, m, 32);
            if (ov > lv || (ov == lv && oe < le)) { lv = ov; le = oe; }
        }
        out[r] = le;
        if ((le >> 2) == l) v[le & 3] = -3.4e38f;   // winner lane retires its slot
    }
    if (l == 0) {
        int4 o0 = {out[0], out[1], out[2], out[3]};
        int4 o1 = {out[4], out[5], out[6], out[7]};
        *(int4*)(cand + (size_t)tok * 8)     = o0;
        *(int4*)(cand + (size_t)tok * 8 + 4) = o1;
    }
}

// ---------------- Kernel 3: exact fp64 recompute of 8 candidates; rank; softmax --------------
__global__ __launch_bounds__(256) void fixup_topk(
    const float* __restrict__ x,
    const float* __restrict__ w,
    const float* __restrict__ bias,
    const int* __restrict__ cand,
    float* __restrict__ vals,
    float* __restrict__ inds)
{
    const int lane = threadIdx.x & 63;
    const int wv   = threadIdx.x >> 6;
    const int tok  = blockIdx.x * 4 + wv;
    const int c    = lane >> 3;         // candidate slot 0..7
    const int s    = lane & 7;          // k-segment
    const int cidx = cand[(size_t)tok * 8 + c];

    const float4* xr = (const float4*)x + (size_t)tok  * H4;
    const float4* wr = (const float4*)w + (size_t)cidx * H4;

    double acc = 0.0;
    for (int j = 0; j < 90; ++j) {
        const float4 a = xr[s + 8 * j];
        const float4 b = wr[s + 8 * j];
        acc = fma((double)a.x, (double)b.x, acc);
        acc = fma((double)a.y, (double)b.y, acc);
        acc = fma((double)a.z, (double)b.z, acc);
        acc = fma((double)a.w, (double)b.w, acc);
    }
    acc += __shfl_xor(acc, 1);
    acc += __shfl_xor(acc, 2);
    acc += __shfl_xor(acc, 4);
    const double exact = acc + (double)bias[cidx];

    double bv[8]; int bidx[8];
#pragma unroll
    for (int g = 0; g < 8; ++g) { bv[g] = __shfl(exact, g * 8); bidx[g] = __shfl(cidx, g * 8); }

    // exact top-4, lax.top_k tie rule (lower expert index wins ties)
    float fv[4]; int fi[4];
#pragma unroll
    for (int k = 0; k < 4; ++k) {
        double best = -1.0e300; int bi = 1 << 30; int bg = -1;
#pragma unroll
        for (int g = 0; g < 8; ++g) {
            if (bv[g] > best || (bv[g] == best && bidx[g] < bi)) { best = bv[g]; bi = bidx[g]; bg = g; }
        }
#pragma unroll
        for (int g = 0; g < 8; ++g) if (g == bg) bv[g] = -1.0e300;
        fv[k] = (float)best; fi[k] = bi;
    }

    if (lane == 0) {
        const float e1 = expf(fv[1] - fv[0]);
        const float e2 = expf(fv[2] - fv[0]);
        const float e3 = expf(fv[3] - fv[0]);
        const float sm = 1.0f + e1 + e2 + e3;
        float4 ov = {1.0f / sm, e1 / sm, e2 / sm, e3 / sm};
        float4 oi = {(float)fi[0], (float)fi[1], (float)fi[2], (float)fi[3]};
        *(float4*)(&vals[(size_t)tok * 4]) = ov;
        *(float4*)(&inds[(size_t)tok * 4]) = oi;
    }
}

extern "C" void kernel_launch(void* const* d_in, const int* in_sizes, int n_in,
                              void* d_out, int out_size, void* d_ws, size_t ws_size,
                              hipStream_t stream) {
    const float* x    = (const float*)d_in[0];
    const float* w    = (const float*)d_in[1];
    const float* bias = (const float*)d_in[2];

    float* out    = (float*)d_out;
    float* vals   = out;                 // 16384*4
    float* inds   = out + NTOK * 4;      // 16384*4
    float* logits = out + NTOK * 8;      // 16384*128

    // ws layout: whi | wlo | pws slices | cand
    const size_t WPLANE = (size_t)NEXP * H * sizeof(short);      // 737280 B
    const size_t PB     = (size_t)NTOK * NEXP * sizeof(float);   // 8.39 MB
    const size_t CB     = (size_t)NTOK * 8 * sizeof(int);        // 512 KB

    int ks = 1;
    if      (ws_size >= 2 * WPLANE + 3 * PB + CB) ks = 4;
    else if (ws_size >= 2 * WPLANE + 2 * PB + CB) ks = 3;
    else if (ws_size >= 2 * WPLANE + 1 * PB + CB) ks = 2;

    short* whi  = (short*)d_ws;
    short* wlo  = whi + (size_t)NEXP * H;
    float* pws  = (float*)(wlo + (size_t)NEXP * H);
    int*   cand = (int*)(pws + (size_t)(ks - 1) * NTOK * NEXP);

    wconv<<<(NEXP * H / 8 + 255) / 256, 256, 0, stream>>>(w, whi, wlo);
    router_gemm_mfma<<<dim3(NTOK / 64, ks), 256, 0, stream>>>(x, whi, wlo, logits, pws);
    reduce_cand<<<NTOK / 8, 256, 0, stream>>>(logits, pws, bias, cand, ks);
    fixup_topk<<<NTOK / 4, 256, 0, stream>>>(x, w, bias, cand, vals, inds);
}

// Round 6
// 184.922 us; speedup vs baseline: 1.3066x; 1.3066x over previous
//
#include <hip/hip_runtime.h>
#include <math.h>

#define H      2880
#define H4     720
#define NTOK   16384
#define NEXP   128
#define NCHUNK 90      // K-chunks of 32 fp32
#define NSTEP  180     // MFMA k-steps of 16

typedef __attribute__((ext_vector_type(8)))  short bf16x8;
typedef __attribute__((ext_vector_type(16))) float f32x16;

union FragU { unsigned int u[4]; bf16x8 v; };

// hi = top 16 bits of fp32 (bf16 truncation); lo = bf16(x - hi).
// (ah+al)(bh+bl) keeps logit err ~1e-5; exact ranking restored by fp64 fixup.
__device__ inline bf16x8 pack_hi2(float4 a, float4 b) {
    const float f[8] = {a.x,a.y,a.z,a.w,b.x,b.y,b.z,b.w};
    FragU r;
#pragma unroll
    for (int j = 0; j < 4; ++j) {
        unsigned u0 = __float_as_uint(f[2*j]);
        unsigned u1 = __float_as_uint(f[2*j+1]);
        r.u[j] = (u1 & 0xFFFF0000u) | (u0 >> 16);
    }
    return r.v;
}
__device__ inline bf16x8 pack_lo2(float4 a, float4 b) {
    const float f[8] = {a.x,a.y,a.z,a.w,b.x,b.y,b.z,b.w};
    FragU r;
#pragma unroll
    for (int j = 0; j < 4; ++j) {
        float x0 = f[2*j],   h0 = __uint_as_float(__float_as_uint(x0) & 0xFFFF0000u);
        float x1 = f[2*j+1], h1 = __uint_as_float(__float_as_uint(x1) & 0xFFFF0000u);
        unsigned l0 = __float_as_uint(x0 - h0);
        unsigned l1 = __float_as_uint(x1 - h1);
        r.u[j] = (l1 & 0xFFFF0000u) | (l0 >> 16);
    }
    return r.v;
}

// ---------------- Kernel 0: w -> bf16 hi/lo planes in MFMA-FRAGMENT order ----------------
// frag idx gid = (s*4 + nt)*64 + lane ; lane l -> expert nt*32+(l&31), k = s*16+(l>>5)*8+0..7
__global__ __launch_bounds__(256) void wconv(
    const float* __restrict__ w, short* __restrict__ whiF, short* __restrict__ wloF)
{
    const int gid = blockIdx.x * 256 + threadIdx.x;   // 180*4*64 = 46080
    const int l   = gid & 63;
    const int nt  = (gid >> 6) & 3;
    const int s   = gid >> 8;
    const int e   = nt * 32 + (l & 31);
    const int k0  = s * 16 + (l >> 5) * 8;
    const float4* wp = (const float4*)(w + (size_t)e * H + k0);
    const float4 a = wp[0], b = wp[1];
    *(bf16x8*)(whiF + (size_t)gid * 8) = pack_hi2(a, b);
    *(bf16x8*)(wloF + (size_t)gid * 8) = pack_lo2(a, b);
}

// ---------------- Kernel 1: MFMA GEMM, LDS-staged A (async, swizzled), frag-ordered B --------
// Block: 256 thr = 4 waves, tile 128 tok x 128 exp; wave = 32 tok x 128 exp. Split-K over y.
__global__ __launch_bounds__(256, 2) void router_gemm_mfma(
    const float* __restrict__ x,        // [NTOK][H] fp32
    const short* __restrict__ whiF,     // fragment-ordered bf16 hi
    const short* __restrict__ wloF,     // fragment-ordered bf16 lo
    float* __restrict__ p0,
    float* __restrict__ pws)
{
    __shared__ float xs[2][128 * 32];   // [buf][slot*4], slot (row,kq) holds global (row, kq^(row&7))

    const int tid  = threadIdx.x;
    const int lane = tid & 63;
    const int wv   = tid >> 6;
    const int bm   = blockIdx.x;
    const int z    = blockIdx.y;
    const int ks   = gridDim.y;
    const int t0   = bm * 128;

    const int base = NCHUNK / ks, rem = NCHUNK % ks;
    const int c0 = z * base + (z < rem ? z : rem);
    const int c1 = c0 + base + (z < rem ? 1 : 0);

    float* outp = (z == 0) ? p0 : (pws + (size_t)(z - 1) * NTOK * NEXP);

    // ---- staging addresses: thread covers slots i*256+tid, i=0..3 (rows srow+32i) ----
    const int srow = tid >> 3;                              // 0..31
    const int skq  = (tid & 7) ^ ((tid >> 3) & 7);          // pre-swizzled source float4
    const float4* gs = (const float4*)x + (size_t)(t0 + srow) * H4 + skq;
    const int ldsbase = (wv * 64) * 4;                      // float offset of this wave's seg

#define STAGE(buf, c) {                                                                      \
    const float4* g_ = gs + (size_t)(c) * 8;                                                 \
    __builtin_amdgcn_global_load_lds((const __attribute__((address_space(1))) void*)(g_),    \
        (__attribute__((address_space(3))) void*)&xs[buf][ldsbase],           16, 0, 0);     \
    __builtin_amdgcn_global_load_lds((const __attribute__((address_space(1))) void*)(g_ + (size_t)32*H4), \
        (__attribute__((address_space(3))) void*)&xs[buf][ldsbase + 1024],    16, 0, 0);     \
    __builtin_amdgcn_global_load_lds((const __attribute__((address_space(1))) void*)(g_ + (size_t)64*H4), \
        (__attribute__((address_space(3))) void*)&xs[buf][ldsbase + 2048],    16, 0, 0);     \
    __builtin_amdgcn_global_load_lds((const __attribute__((address_space(1))) void*)(g_ + (size_t)96*H4), \
        (__attribute__((address_space(3))) void*)&xs[buf][ldsbase + 3072],    16, 0, 0); }

    // ---- compute-side addressing ----
    const int rbaseF = (wv * 32 + (lane & 31)) * 32;        // my row's float base in tile
    const int lx7    = lane & 7;
    const int kh2    = (lane >> 5) * 2;                     // float4 pair offset within step

    f32x16 acc[4];
#pragma unroll
    for (int nt = 0; nt < 4; ++nt)
#pragma unroll
        for (int r = 0; r < 16; ++r) acc[nt][r] = 0.0f;

    STAGE(0, c0);
    __syncthreads();

    int cur = 0;
    for (int c = c0; c < c1; ++c) {
        if (c + 1 < c1) STAGE(cur ^ 1, c + 1);

#pragma unroll
        for (int st = 0; st < 2; ++st) {
            const int kq0 = st * 4 + kh2;
            const float4 f0 = *(const float4*)&xs[cur][rbaseF + (((kq0    ) ^ lx7) << 2)];
            const float4 f1 = *(const float4*)&xs[cur][rbaseF + (((kq0 + 1) ^ lx7) << 2)];
            const bf16x8 ah = pack_hi2(f0, f1);
            const bf16x8 al = pack_lo2(f0, f1);
            const int s = c * 2 + st;
#pragma unroll
            for (int nt = 0; nt < 4; ++nt) {
                const size_t fo = ((size_t)(s * 4 + nt) * 64 + lane) * 8;
                const bf16x8 bh = *(const bf16x8*)(whiF + fo);
                const bf16x8 bl = *(const bf16x8*)(wloF + fo);
                acc[nt] = __builtin_amdgcn_mfma_f32_32x32x16_bf16(ah, bh, acc[nt], 0, 0, 0);
                acc[nt] = __builtin_amdgcn_mfma_f32_32x32x16_bf16(al, bh, acc[nt], 0, 0, 0);
                acc[nt] = __builtin_amdgcn_mfma_f32_32x32x16_bf16(ah, bl, acc[nt], 0, 0, 0);
            }
        }

        __syncthreads();     // drains stage loads (vmcnt0) + protects buffer swap
        cur ^= 1;
    }

    // D layout (32x32): col = lane&31, row = (r&3) + 8*(r>>2) + 4*(lane>>5)  [R4/R5-verified]
    const int ecol  = lane & 31;
    const int rbase = t0 + wv * 32 + 4 * (lane >> 5);
#pragma unroll
    for (int nt = 0; nt < 4; ++nt)
#pragma unroll
        for (int r = 0; r < 16; ++r) {
            const int orow = rbase + (r & 3) + 8 * (r >> 2);
            outp[(size_t)orow * NEXP + nt * 32 + ecol] = acc[nt][r];
        }
}

// ---------------- Kernel 2: reduce slices + bias -> logits; approx top-8 (wave-parallel) -----
__global__ __launch_bounds__(256) void reduce_cand(
    float* __restrict__ p0,
    const float* __restrict__ pws,
    const float* __restrict__ bias,
    int* __restrict__ cand,             // [NTOK][8]
    int ks)
{
    const int tid = threadIdx.x;
    const int tok = blockIdx.x * 8 + (tid >> 5);
    const int l   = tid & 31;

    float4* row = (float4*)p0 + (size_t)tok * 32 + l;
    float4 s = row[0];
    for (int zz = 1; zz < ks; ++zz) {
        const float4 pz = ((const float4*)(pws + (size_t)(zz - 1) * NTOK * NEXP))[(size_t)tok * 32 + l];
        s.x += pz.x; s.y += pz.y; s.z += pz.z; s.w += pz.w;
    }
    const float4 bb = ((const float4*)bias)[l];
    s.x += bb.x; s.y += bb.y; s.z += bb.z; s.w += bb.w;
    row[0] = s;                         // final (approx) logits

    float v[4] = {s.x, s.y, s.z, s.w};
    int out[8];
#pragma unroll
    for (int r = 0; r < 8; ++r) {
        float lv = v[0]; int lj = 0;
#pragma unroll
        for (int j = 1; j < 4; ++j) if (v[j] > lv) { lv = v[j]; lj = j; }
        int le = l * 4 + lj;
#pragma unroll
        for (int m = 1; m < 32; m <<= 1) {
            const float ov = __shfl_xor(lv, m, 32);
            const int   oe = __shfl_xor(le, m, 32);
            if (ov > lv || (ov == lv && oe < le)) { lv = ov; le = oe; }
        }
        out[r] = le;
        if ((le >> 2) == l) v[le & 3] = -3.4e38f;
    }
    if (l == 0) {
        int4 o0 = {out[0], out[1], out[2], out[3]};
        int4 o1 = {out[4], out[5], out[6], out[7]};
        *(int4*)(cand + (size_t)tok * 8)     = o0;
        *(int4*)(cand + (size_t)tok * 8 + 4) = o1;
    }
}

// ---------------- Kernel 3: exact fp64 recompute of 8 candidates; rank; softmax --------------
__global__ __launch_bounds__(256) void fixup_topk(
    const float* __restrict__ x,
    const float* __restrict__ w,
    const float* __restrict__ bias,
    const int* __restrict__ cand,
    float* __restrict__ vals,
    float* __restrict__ inds)
{
    const int lane = threadIdx.x & 63;
    const int wv   = threadIdx.x >> 6;
    const int tok  = blockIdx.x * 4 + wv;
    const int c    = lane >> 3;
    const int s    = lane & 7;
    const int cidx = cand[(size_t)tok * 8 + c];

    const float4* xr = (const float4*)x + (size_t)tok  * H4;
    const float4* wr = (const float4*)w + (size_t)cidx * H4;

    double acc = 0.0;
    for (int j = 0; j < 90; ++j) {
        const float4 a = xr[s + 8 * j];
        const float4 b = wr[s + 8 * j];
        acc = fma((double)a.x, (double)b.x, acc);
        acc = fma((double)a.y, (double)b.y, acc);
        acc = fma((double)a.z, (double)b.z, acc);
        acc = fma((double)a.w, (double)b.w, acc);
    }
    acc += __shfl_xor(acc, 1);
    acc += __shfl_xor(acc, 2);
    acc += __shfl_xor(acc, 4);
    const double exact = acc + (double)bias[cidx];

    double bv[8]; int bidx[8];
#pragma unroll
    for (int g = 0; g < 8; ++g) { bv[g] = __shfl(exact, g * 8); bidx[g] = __shfl(cidx, g * 8); }

    float fv[4]; int fi[4];
#pragma unroll
    for (int k = 0; k < 4; ++k) {
        double best = -1.0e300; int bi = 1 << 30; int bg = -1;
#pragma unroll
        for (int g = 0; g < 8; ++g) {
            if (bv[g] > best || (bv[g] == best && bidx[g] < bi)) { best = bv[g]; bi = bidx[g]; bg = g; }
        }
#pragma unroll
        for (int g = 0; g < 8; ++g) if (g == bg) bv[g] = -1.0e300;
        fv[k] = (float)best; fi[k] = bi;
    }

    if (lane == 0) {
        const float e1 = expf(fv[1] - fv[0]);
        const float e2 = expf(fv[2] - fv[0]);
        const float e3 = expf(fv[3] - fv[0]);
        const float sm = 1.0f + e1 + e2 + e3;
        float4 ov = {1.0f / sm, e1 / sm, e2 / sm, e3 / sm};
        float4 oi = {(float)fi[0], (float)fi[1], (float)fi[2], (float)fi[3]};
        *(float4*)(&vals[(size_t)tok * 4]) = ov;
        *(float4*)(&inds[(size_t)tok * 4]) = oi;
    }
}

extern "C" void kernel_launch(void* const* d_in, const int* in_sizes, int n_in,
                              void* d_out, int out_size, void* d_ws, size_t ws_size,
                              hipStream_t stream) {
    const float* x    = (const float*)d_in[0];
    const float* w    = (const float*)d_in[1];
    const float* bias = (const float*)d_in[2];

    float* out    = (float*)d_out;
    float* vals   = out;                 // 16384*4
    float* inds   = out + NTOK * 4;      // 16384*4
    float* logits = out + NTOK * 8;      // 16384*128

    // ws layout: whiF | wloF | pws slices | cand
    const size_t WPLANE = (size_t)NEXP * H * sizeof(short);      // 737280 B
    const size_t PB     = (size_t)NTOK * NEXP * sizeof(float);   // 8.39 MB
    const size_t CB     = (size_t)NTOK * 8 * sizeof(int);        // 512 KB

    int ks = 1;
    if      (ws_size >= 2 * WPLANE + 3 * PB + CB) ks = 4;
    else if (ws_size >= 2 * WPLANE + 1 * PB + CB) ks = 2;

    short* whiF = (short*)d_ws;
    short* wloF = whiF + (size_t)NEXP * H;
    float* pws  = (float*)(wloF + (size_t)NEXP * H);
    int*   cand = (int*)(pws + (size_t)(ks - 1) * NTOK * NEXP);

    wconv<<<NSTEP, 256, 0, stream>>>(w, whiF, wloF);
    router_gemm_mfma<<<dim3(NTOK / 128, ks), 256, 0, stream>>>(x, whiF, wloF, logits, pws);
    reduce_cand<<<NTOK / 8, 256, 0, stream>>>(logits, pws, bias, cand, ks);
    fixup_topk<<<NTOK / 4, 256, 0, stream>>>(x, w, bias, cand, vals, inds);
}

// Round 7
// 87.038 us; speedup vs baseline: 2.7761x; 2.1246x over previous
//
#include <hip/hip_runtime.h>
#include <math.h>

#define H       2880
#define H4      720
#define NTOK    16384
#define NEXP    128
#define NCHUNK  90      // K-chunks of 32 fp32
#define NSTEP   180
#define GAP_EPS 1e-3f   // approx-ranking trust margin (err rms ~7e-6)

typedef __attribute__((ext_vector_type(8)))  short bf16x8;
typedef __attribute__((ext_vector_type(16))) float f32x16;

union FragU { unsigned int u[4]; bf16x8 v; };

// hi = top 16 bits of fp32 (bf16 truncation); lo = bf16(x - hi).
__device__ inline bf16x8 pack_hi2(float4 a, float4 b) {
    const float f[8] = {a.x,a.y,a.z,a.w,b.x,b.y,b.z,b.w};
    FragU r;
#pragma unroll
    for (int j = 0; j < 4; ++j) {
        unsigned u0 = __float_as_uint(f[2*j]);
        unsigned u1 = __float_as_uint(f[2*j+1]);
        r.u[j] = (u1 & 0xFFFF0000u) | (u0 >> 16);
    }
    return r.v;
}
__device__ inline bf16x8 pack_lo2(float4 a, float4 b) {
    const float f[8] = {a.x,a.y,a.z,a.w,b.x,b.y,b.z,b.w};
    FragU r;
#pragma unroll
    for (int j = 0; j < 4; ++j) {
        float x0 = f[2*j],   h0 = __uint_as_float(__float_as_uint(x0) & 0xFFFF0000u);
        float x1 = f[2*j+1], h1 = __uint_as_float(__float_as_uint(x1) & 0xFFFF0000u);
        unsigned l0 = __float_as_uint(x0 - h0);
        unsigned l1 = __float_as_uint(x1 - h1);
        r.u[j] = (l1 & 0xFFFF0000u) | (l0 >> 16);
    }
    return r.v;
}

// ---------------- Kernel 0: w -> bf16 hi/lo planes in MFMA-FRAGMENT order ----------------
__global__ __launch_bounds__(256) void wconv(
    const float* __restrict__ w, short* __restrict__ whiF, short* __restrict__ wloF)
{
    const int gid = blockIdx.x * 256 + threadIdx.x;   // 180*4*64 = 46080
    const int l   = gid & 63;
    const int nt  = (gid >> 6) & 3;
    const int s   = gid >> 8;
    const int e   = nt * 32 + (l & 31);
    const int k0  = s * 16 + (l >> 5) * 8;
    const float4* wp = (const float4*)(w + (size_t)e * H + k0);
    const float4 a = wp[0], b = wp[1];
    *(bf16x8*)(whiF + (size_t)gid * 8) = pack_hi2(a, b);
    *(bf16x8*)(wloF + (size_t)gid * 8) = pack_lo2(a, b);
}

// ---------------- Kernel 1: wave-autonomous MFMA GEMM, counted-vmcnt pipeline ----------------
// 1 wave per block (32 tok x 128 exp). A: 3-buffer LDS staging (global_load_lds, wave-private,
// no barriers). B: double-banked register prefetch from fragment-ordered planes.
__global__ __launch_bounds__(64, 2) void router_gemm_mfma(
    const float* __restrict__ x,
    const short* __restrict__ whiF,
    const short* __restrict__ wloF,
    float* __restrict__ p0,
    float* __restrict__ pws)
{
    __shared__ float xs[3][1024];       // 12 KB, wave-private

    const int lane = threadIdx.x;
    const int bm   = blockIdx.x;        // 0..511
    const int z    = blockIdx.y;
    const int ks   = gridDim.y;
    const int t0   = bm * 32;

    const int base = NCHUNK / ks, rem = NCHUNK % ks;
    const int c0 = z * base + (z < rem ? z : rem);
    const int c1 = c0 + base + (z < rem ? 1 : 0);   // c1-c0 >= 22 for ks<=4

    float* outp = (z == 0) ? p0 : (pws + (size_t)(z - 1) * NTOK * NEXP);

    // stage source: lane l covers rows (l>>3)+8i, pre-swizzled col (l&7)^(l>>3)
    const float4* gs = (const float4*)x + (size_t)(t0 + (lane >> 3)) * H4 + ((lane & 7) ^ (lane >> 3));
    const unsigned xsb = (unsigned)(uintptr_t)&xs[0][0];
    const int r31 = lane & 31, lx7 = lane & 7, kh2 = (lane >> 5) * 2;

    f32x16 acc[4];
#pragma unroll
    for (int nt = 0; nt < 4; ++nt)
#pragma unroll
        for (int r = 0; r < 16; ++r) acc[nt][r] = 0.0f;

    bf16x8 bc[16], bn[16];

#define GL(SRC, DST) __builtin_amdgcn_global_load_lds(                                   \
        (const __attribute__((address_space(1))) void*)(SRC),                            \
        (__attribute__((address_space(3))) void*)(DST), 16, 0, 0)

#define STAGE(SB, CC) {                                                                  \
    const float4* g_ = gs + (size_t)(CC) * 8;                                            \
    GL(g_,                  &xs[SB][0]);                                                 \
    GL(g_ + (size_t) 8*H4,  &xs[SB][256]);                                               \
    GL(g_ + (size_t)16*H4,  &xs[SB][512]);                                               \
    GL(g_ + (size_t)24*H4,  &xs[SB][768]); }

#define BLOAD_ST(DST, CC, ST) {                                                          \
    _Pragma("unroll")                                                                    \
    for (int nt = 0; nt < 4; ++nt) {                                                     \
        const size_t o_ = ((size_t)(((CC)*2 + (ST))*4 + nt)*64 + lane) * 8;              \
        DST[(ST)*8 + nt*2]     = *(const bf16x8*)(whiF + o_);                            \
        DST[(ST)*8 + nt*2 + 1] = *(const bf16x8*)(wloF + o_); } }

#define MFMA_ST(ST, AH, AL) {                                                            \
    _Pragma("unroll")                                                                    \
    for (int nt = 0; nt < 4; ++nt) {                                                     \
        acc[nt] = __builtin_amdgcn_mfma_f32_32x32x16_bf16(AH, bc[(ST)*8 + nt*2],     acc[nt], 0,0,0); \
        acc[nt] = __builtin_amdgcn_mfma_f32_32x32x16_bf16(AL, bc[(ST)*8 + nt*2],     acc[nt], 0,0,0); \
        acc[nt] = __builtin_amdgcn_mfma_f32_32x32x16_bf16(AH, bc[(ST)*8 + nt*2 + 1], acc[nt], 0,0,0); } }

#define BODY(C, DOB) {                                                                   \
    const unsigned ab  = xsb + (unsigned)rb * 4096u + (unsigned)r31 * 128u;              \
    const unsigned a00 = ab + 16u * (unsigned)((kh2    ) ^ lx7);                         \
    const unsigned a01 = ab + 16u * (unsigned)((kh2 + 1) ^ lx7);                         \
    const unsigned a10 = ab + 16u * (unsigned)((kh2 + 4) ^ lx7);                         \
    const unsigned a11 = ab + 16u * (unsigned)((kh2 + 5) ^ lx7);                         \
    float4 q0, q1, q2, q3;                                                               \
    asm volatile("ds_read_b128 %0, %1" : "=v"(q0) : "v"(a00) : "memory");                \
    asm volatile("ds_read_b128 %0, %1" : "=v"(q1) : "v"(a01) : "memory");                \
    asm volatile("ds_read_b128 %0, %1" : "=v"(q2) : "v"(a10) : "memory");                \
    asm volatile("ds_read_b128 %0, %1" : "=v"(q3) : "v"(a11) : "memory");                \
    asm volatile("s_waitcnt lgkmcnt(0)" ::: "memory");                                   \
    __builtin_amdgcn_sched_barrier(0);                                                   \
    const bf16x8 ah0 = pack_hi2(q0, q1), al0 = pack_lo2(q0, q1);                         \
    const bf16x8 ah1 = pack_hi2(q2, q3), al1 = pack_lo2(q2, q3);                         \
    if (DOB) BLOAD_ST(bn, (C) + 1, 0);                                                   \
    MFMA_ST(0, ah0, al0);                                                                \
    if (DOB) BLOAD_ST(bn, (C) + 1, 1);                                                   \
    MFMA_ST(1, ah1, al1);                                                                \
    if (DOB) { _Pragma("unroll") for (int i_ = 0; i_ < 16; ++i_) bc[i_] = bn[i_]; }      \
    rb = (rb == 2) ? 0 : rb + 1; }

#define ITER(C, DOSTAGE, VMSTR, DOB) {                                                   \
    if (DOSTAGE) { STAGE(sb, (C) + 2); sb = (sb == 2) ? 0 : sb + 1; }                    \
    asm volatile("s_waitcnt vmcnt(" VMSTR ")" ::: "memory");                             \
    BODY((C), DOB) }

    int rb = c0 % 3;
    int sb = rb + 2; if (sb >= 3) sb -= 3;
    int b1 = rb + 1; if (b1 >= 3) b1 -= 3;

    // prologue: S(c0), S(c0+1), B(c0)
    STAGE(rb, c0);
    STAGE(b1, c0 + 1);
    BLOAD_ST(bc, c0, 0);
    BLOAD_ST(bc, c0, 1);

    // issue-order bookkeeping (in-order vmcnt retirement):
    //  iter c0:    younger-than-S(c0)   = S(c0+1)4 + B(c0)16 + S(c0+2)4           = 24
    //  iter c0+1+: younger-than-S(c)    = B(c-1)16 + S(c+1)4 + B(c)16 + S(c+2)4   = 40
    //  iter c1-2:  (no S(c1))           = 36
    //  iter c1-1:  (no S(c1), no B(c1)) = 32
    ITER(c0,     true,  "24", true);
    ITER(c0 + 1, true,  "40", true);
    for (int c = c0 + 2; c < c1 - 2; ++c) {
        ITER(c, true, "40", true);
    }
    ITER(c1 - 2, false, "36", true);
    ITER(c1 - 1, false, "32", false);

    // D layout (32x32): col = lane&31, row = (r&3) + 8*(r>>2) + 4*(lane>>5)  [verified]
    const int ecol  = lane & 31;
    const int rbase = t0 + 4 * (lane >> 5);
#pragma unroll
    for (int nt = 0; nt < 4; ++nt)
#pragma unroll
        for (int r = 0; r < 16; ++r) {
            const int orow = rbase + (r & 3) + 8 * (r >> 2);
            outp[(size_t)orow * NEXP + nt * 32 + ecol] = acc[nt][r];
        }
}

// ---------------- Kernel 2: reduce + bias -> logits; top-8; gap-gated fast path --------------
__global__ __launch_bounds__(256) void reduce_cand(
    float* __restrict__ p0,
    const float* __restrict__ pws,
    const float* __restrict__ bias,
    int* __restrict__ cand,             // [NTOK][8]; cand[t*8] bit30 = needs exact fixup
    float* __restrict__ vals,
    float* __restrict__ inds,
    int ks)
{
    const int tid = threadIdx.x;
    const int tok = blockIdx.x * 8 + (tid >> 5);
    const int l   = tid & 31;

    float4* row = (float4*)p0 + (size_t)tok * 32 + l;
    float4 s = row[0];
    for (int zz = 1; zz < ks; ++zz) {
        const float4 pz = ((const float4*)(pws + (size_t)(zz - 1) * NTOK * NEXP))[(size_t)tok * 32 + l];
        s.x += pz.x; s.y += pz.y; s.z += pz.z; s.w += pz.w;
    }
    const float4 bb = ((const float4*)bias)[l];
    s.x += bb.x; s.y += bb.y; s.z += bb.z; s.w += bb.w;
    row[0] = s;                         // final (approx) logits

    float v[4] = {s.x, s.y, s.z, s.w};
    float vv[8]; int out[8];
#pragma unroll
    for (int r = 0; r < 8; ++r) {
        float lv = v[0]; int lj = 0;
#pragma unroll
        for (int j = 1; j < 4; ++j) if (v[j] > lv) { lv = v[j]; lj = j; }
        int le = l * 4 + lj;
#pragma unroll
        for (int m = 1; m < 32; m <<= 1) {
            const float ov = __shfl_xor(lv, m, 32);
            const int   oe = __shfl_xor(le, m, 32);
            if (ov > lv || (ov == lv && oe < le)) { lv = ov; le = oe; }
        }
        vv[r] = lv; out[r] = le;
        if ((le >> 2) == l) v[le & 3] = -3.4e38f;
    }

    // if all adjacent gaps among approx top-5 exceed GAP_EPS, approx ranking is exact
    float ming = vv[0] - vv[1];
    ming = fminf(ming, vv[1] - vv[2]);
    ming = fminf(ming, vv[2] - vv[3]);
    ming = fminf(ming, vv[3] - vv[4]);
    const bool slow = (ming < GAP_EPS);

    if (l == 0) {
        int4 o0 = {out[0] | (slow ? (1 << 30) : 0), out[1], out[2], out[3]};
        int4 o1 = {out[4], out[5], out[6], out[7]};
        *(int4*)(cand + (size_t)tok * 8)     = o0;
        *(int4*)(cand + (size_t)tok * 8 + 4) = o1;
        if (!slow) {
            const float e1 = expf(vv[1] - vv[0]);
            const float e2 = expf(vv[2] - vv[0]);
            const float e3 = expf(vv[3] - vv[0]);
            const float sm = 1.0f + e1 + e2 + e3;
            float4 ov = {1.0f / sm, e1 / sm, e2 / sm, e3 / sm};
            float4 oi = {(float)out[0], (float)out[1], (float)out[2], (float)out[3]};
            *(float4*)(&vals[(size_t)tok * 4]) = ov;
            *(float4*)(&inds[(size_t)tok * 4]) = oi;
        }
    }
}

// ---------------- Kernel 3: exact fp64 recompute, only for flagged tokens --------------------
__global__ __launch_bounds__(256) void fixup_topk(
    const float* __restrict__ x,
    const float* __restrict__ w,
    const float* __restrict__ bias,
    const int* __restrict__ cand,
    float* __restrict__ vals,
    float* __restrict__ inds)
{
    const int lane = threadIdx.x & 63;
    const int wv   = threadIdx.x >> 6;
    const int tok  = blockIdx.x * 4 + wv;

    const int head = cand[(size_t)tok * 8];
    if (!(head & (1 << 30))) return;    // fast-path token, already written by reduce_cand

    const int c    = lane >> 3;
    const int s    = lane & 7;
    const int cidx = cand[(size_t)tok * 8 + c] & 0x3fffffff;

    const float4* xr = (const float4*)x + (size_t)tok  * H4;
    const float4* wr = (const float4*)w + (size_t)cidx * H4;

    double acc = 0.0;
    for (int j = 0; j < 90; ++j) {
        const float4 a = xr[s + 8 * j];
        const float4 b = wr[s + 8 * j];
        acc = fma((double)a.x, (double)b.x, acc);
        acc = fma((double)a.y, (double)b.y, acc);
        acc = fma((double)a.z, (double)b.z, acc);
        acc = fma((double)a.w, (double)b.w, acc);
    }
    acc += __shfl_xor(acc, 1);
    acc += __shfl_xor(acc, 2);
    acc += __shfl_xor(acc, 4);
    const double exact = acc + (double)bias[cidx];

    double bv[8]; int bidx[8];
#pragma unroll
    for (int g = 0; g < 8; ++g) { bv[g] = __shfl(exact, g * 8); bidx[g] = __shfl(cidx, g * 8); }

    float fv[4]; int fi[4];
#pragma unroll
    for (int k = 0; k < 4; ++k) {
        double best = -1.0e300; int bi = 1 << 30; int bg = -1;
#pragma unroll
        for (int g = 0; g < 8; ++g) {
            if (bv[g] > best || (bv[g] == best && bidx[g] < bi)) { best = bv[g]; bi = bidx[g]; bg = g; }
        }
#pragma unroll
        for (int g = 0; g < 8; ++g) if (g == bg) bv[g] = -1.0e300;
        fv[k] = (float)best; fi[k] = bi;
    }

    if (lane == 0) {
        const float e1 = expf(fv[1] - fv[0]);
        const float e2 = expf(fv[2] - fv[0]);
        const float e3 = expf(fv[3] - fv[0]);
        const float sm = 1.0f + e1 + e2 + e3;
        float4 ov = {1.0f / sm, e1 / sm, e2 / sm, e3 / sm};
        float4 oi = {(float)fi[0], (float)fi[1], (float)fi[2], (float)fi[3]};
        *(float4*)(&vals[(size_t)tok * 4]) = ov;
        *(float4*)(&inds[(size_t)tok * 4]) = oi;
    }
}

extern "C" void kernel_launch(void* const* d_in, const int* in_sizes, int n_in,
                              void* d_out, int out_size, void* d_ws, size_t ws_size,
                              hipStream_t stream) {
    const float* x    = (const float*)d_in[0];
    const float* w    = (const float*)d_in[1];
    const float* bias = (const float*)d_in[2];

    float* out    = (float*)d_out;
    float* vals   = out;                 // 16384*4
    float* inds   = out + NTOK * 4;      // 16384*4
    float* logits = out + NTOK * 8;      // 16384*128

    const size_t WPLANE = (size_t)NEXP * H * sizeof(short);      // 737280 B
    const size_t PB     = (size_t)NTOK * NEXP * sizeof(float);   // 8.39 MB
    const size_t CB     = (size_t)NTOK * 8 * sizeof(int);        // 512 KB

    int ks = 1;
    if      (ws_size >= 2 * WPLANE + 3 * PB + CB) ks = 4;
    else if (ws_size >= 2 * WPLANE + 1 * PB + CB) ks = 2;

    short* whiF = (short*)d_ws;
    short* wloF = whiF + (size_t)NEXP * H;
    float* pws  = (float*)(wloF + (size_t)NEXP * H);
    int*   cand = (int*)(pws + (size_t)(ks - 1) * NTOK * NEXP);

    wconv<<<NSTEP, 256, 0, stream>>>(w, whiF, wloF);
    router_gemm_mfma<<<dim3(NTOK / 32, ks), 64, 0, stream>>>(x, whiF, wloF, logits, pws);
    reduce_cand<<<NTOK / 8, 256, 0, stream>>>(logits, pws, bias, cand, vals, inds, ks);
    fixup_topk<<<NTOK / 4, 256, 0, stream>>>(x, w, bias, cand, vals, inds);
}